// Round 15
// baseline (637.240 us; speedup 1.0000x reference)
//
#include <hip/hip_runtime.h>
#include <hip/hip_fp16.h>

// R14 post-mortem: fp16 halved aggmain FETCH (262->134MB) but time unchanged
// (117->118us, VALU 62->71%) -> aggmain is issue/latency-bound, not byte-bound.
// R15: kill the 112us CSR-build chain (count 73us = 1.6M device atomics at
// ~22G/s write-through floor + scatter 25 + scan 12): dst-range-partitioned
// build with LDS atomics. 98 ranges x 4 edge-chunks; block scans its chunk's
// dst array, owns dsts [r*512, r*512+512), slot from LDS counter, writes
// csrf[d*128 + c*32 + slot] directly. chunk-deg ~ Poisson(8), cap 32 safe.
// 9 -> 4 launches; zero global atomics.

#define NN 50000
#define EE 1600000
#define FT 96        // F*T
#define TP 12
#define FF 8
#define HH 64
#define RB 512       // dst range per block
#define NCH 4        // edge chunks
#define CHE 400000   // EE / NCH
#define CCAP 32      // slots per (node, chunk); chunk-deg ~ Poisson(8)
#define CAP 128      // NCH * CCAP
#define NRANGE 98    // ceil(NN / RB)

union Cv { ushort4 u; __half2 h[2]; };

// one block per (range, chunk): LDS-atomic slot assign + direct scatter
__global__ void __launch_bounds__(256) k_build2(const int* __restrict__ ei,
                                                const float* __restrict__ ea,
                                                int* __restrict__ counts2,   // [NCH][NN]
                                                int2* __restrict__ csrf) {   // [NN][NCH][CCAP]
    int r = blockIdx.x / NCH;
    int c = blockIdx.x % NCH;
    int base = r * RB;
    __shared__ int lcnt[RB];
    for (int i = threadIdx.x; i < RB; i += 256) lcnt[i] = 0;
    __syncthreads();
    const int* dst = ei + EE;
    int ebeg = c * CHE, eend = ebeg + CHE;
    for (int e = ebeg + threadIdx.x; e < eend; e += 256) {
        int d = dst[e];
        unsigned rel = (unsigned)(d - base);
        if (rel < RB) {
            int slot = atomicAdd(&lcnt[rel], 1);   // LDS atomic
            if (slot < CCAP)
                csrf[(size_t)d * CAP + c * CCAP + slot] =
                    make_int2(ei[e], __float_as_int(ea[e]));
        }
    }
    __syncthreads();
    for (int i = threadIdx.x; i < RB; i += 256) {
        int n = base + i;
        if (n < NN) counts2[c * NN + n] = min(lcnt[i], CCAP);
    }
}

// wave per node: deg = 1 + sum(ea row); dinv = rsqrt(deg); xs = fp16(dinv * x)
// per chunk cnt <= 32 < 64 -> one predicated load per chunk, no loop.
__global__ void __launch_bounds__(256) k_degxs(const float* __restrict__ x,
                                               const int* __restrict__ counts2,
                                               const int2* __restrict__ csrf,
                                               float* __restrict__ dinv,
                                               __half* __restrict__ xsh) {
    int wave = threadIdx.x >> 6;
    int lane = threadIdx.x & 63;
    int n = blockIdx.x * 4 + wave;
    if (n >= NN) return;
    float s = 0.0f;
    #pragma unroll
    for (int c = 0; c < NCH; c++) {
        int cnt = counts2[c * NN + n];
        if (lane < cnt)
            s += __int_as_float(csrf[(size_t)n * CAP + c * CCAP + lane].y);
    }
    for (int off = 32; off > 0; off >>= 1) s += __shfl_xor(s, off, 64);
    float di = rsqrtf(1.0f + s);   // deg >= 1 always (self loop weight 1, ea >= 0)
    if (lane == 0) dinv[n] = di;
    if (lane < 24) {
        float4 v = ((const float4*)(x + (size_t)n * FT))[lane];
        Cv cc;
        cc.h[0] = __floats2half2_rn(di * v.x, di * v.y);
        cc.h[1] = __floats2half2_rn(di * v.z, di * v.w);
        ((ushort4*)xsh)[(size_t)n * 24 + lane] = cc.u;
    }
}

// fold: Mz = Wz @ Wlz_top (8x64), Mh = Wh @ Wlh_top, folded biases, probs = softmax(att)
__global__ void __launch_bounds__(64) k_fold(const float* Wz, const float* bz,
                                             const float* Wh, const float* bh,
                                             const float* Wlz, const float* blz,
                                             const float* Wlh, const float* blh,
                                             const float* att, float* fold) {
    int h = threadIdx.x;   // 0..63
    for (int f = 0; f < FF; f++) {
        float sz = 0.0f, sh = 0.0f;
        for (int k = 0; k < HH; k++) {
            sz += Wz[f * HH + k] * Wlz[k * HH + h];
            sh += Wh[f * HH + k] * Wlh[k * HH + h];
        }
        fold[f * HH + h]       = sz;   // Mz
        fold[512 + f * HH + h] = sh;   // Mh
    }
    float cz = blz[h], ch = blh[h];
    for (int k = 0; k < HH; k++) {
        cz += bz[k] * Wlz[k * HH + h];
        ch += bh[k] * Wlh[k * HH + h];
    }
    fold[1024 + h] = cz;
    fold[1088 + h] = ch;
    if (h < TP) {
        float m = -1e30f;
        for (int t = 0; t < TP; t++) m = fmaxf(m, att[t]);
        float s = 0.0f;
        for (int t = 0; t < TP; t++) s += __expf(att[t] - m);
        fold[1152 + h] = __expf(att[h] - m) / s;
    }
}

// fused: wave-per-node gather (24 lanes x ushort4 fp16 row) over 4 chunk
// segments -> row in per-wave LDS -> lane=h epilogue -> shfl butterfly o[j].
__global__ void __launch_bounds__(256) k_aggmain(const __half* __restrict__ xsh,
                                                 const float* __restrict__ dinv,
                                                 const int* __restrict__ counts2,
                                                 const int2* __restrict__ csrf,
                                                 const float* __restrict__ fold,
                                                 const float* __restrict__ Wout,
                                                 const float* __restrict__ bout,
                                                 float* __restrict__ out) {
    __shared__ float sMz[512], sMh[512], sczb[64], schb[64], sprobs[16], sWout[768], sbout[16];
    __shared__ float sy[4][FT];
    for (int i = threadIdx.x; i < 512; i += 256) { sMz[i] = fold[i]; sMh[i] = fold[512 + i]; }
    if (threadIdx.x < 64) {
        sczb[threadIdx.x] = fold[1024 + threadIdx.x];
        schb[threadIdx.x] = fold[1088 + threadIdx.x];
    }
    if (threadIdx.x < TP) {
        sprobs[threadIdx.x] = fold[1152 + threadIdx.x];
        sbout[threadIdx.x]  = bout[threadIdx.x];
    }
    for (int i = threadIdx.x; i < 768; i += 256) sWout[i] = Wout[i];

    int wave = threadIdx.x >> 6;
    int lane = threadIdx.x & 63;
    int n = blockIdx.x * 4 + wave;

    const ushort4* xsr = (const ushort4*)xsh;   // 24 ushort4 per row

    // ---- gather: agg_row = dinv[n] * (xs[n] + sum_e ea_e * xs[src_e]) ----
    bool act = lane < 24;
    float ax = 0.0f, ay = 0.0f, az = 0.0f, aw = 0.0f;
    if (act) {
        Cv c; c.u = xsr[(size_t)n * 24 + lane];
        float2 a = __half22float2(c.h[0]);
        float2 b = __half22float2(c.h[1]);
        ax = a.x; ay = a.y; az = b.x; aw = b.y;
    }
    #pragma unroll
    for (int ch = 0; ch < NCH; ch++) {
        int cnt = __builtin_amdgcn_readfirstlane(counts2[ch * NN + n]);
        int jb = __builtin_amdgcn_readfirstlane(n * CAP + ch * CCAP);
        int je = jb + cnt;
        int j = jb;
        for (; j + 4 <= je; j += 4) {
            int2 m0 = csrf[j];
            int2 m1 = csrf[j + 1];
            int2 m2 = csrf[j + 2];
            int2 m3 = csrf[j + 3];
            if (act) {
                Cv c0, c1, c2, c3;
                c0.u = xsr[(size_t)m0.x * 24 + lane];
                c1.u = xsr[(size_t)m1.x * 24 + lane];
                c2.u = xsr[(size_t)m2.x * 24 + lane];
                c3.u = xsr[(size_t)m3.x * 24 + lane];
                float w0_ = __int_as_float(m0.y);
                float w1_ = __int_as_float(m1.y);
                float w2_ = __int_as_float(m2.y);
                float w3_ = __int_as_float(m3.y);
                float2 a0 = __half22float2(c0.h[0]), b0 = __half22float2(c0.h[1]);
                float2 a1 = __half22float2(c1.h[0]), b1 = __half22float2(c1.h[1]);
                float2 a2 = __half22float2(c2.h[0]), b2 = __half22float2(c2.h[1]);
                float2 a3 = __half22float2(c3.h[0]), b3 = __half22float2(c3.h[1]);
                ax = fmaf(w0_, a0.x, ax); ay = fmaf(w0_, a0.y, ay);
                az = fmaf(w0_, b0.x, az); aw = fmaf(w0_, b0.y, aw);
                ax = fmaf(w1_, a1.x, ax); ay = fmaf(w1_, a1.y, ay);
                az = fmaf(w1_, b1.x, az); aw = fmaf(w1_, b1.y, aw);
                ax = fmaf(w2_, a2.x, ax); ay = fmaf(w2_, a2.y, ay);
                az = fmaf(w2_, b2.x, az); aw = fmaf(w2_, b2.y, aw);
                ax = fmaf(w3_, a3.x, ax); ay = fmaf(w3_, a3.y, ay);
                az = fmaf(w3_, b3.x, az); aw = fmaf(w3_, b3.y, aw);
            }
        }
        for (; j < je; j++) {
            int2 m = csrf[j];
            if (act) {
                Cv c; c.u = xsr[(size_t)m.x * 24 + lane];
                float wgt = __int_as_float(m.y);
                float2 a = __half22float2(c.h[0]);
                float2 b = __half22float2(c.h[1]);
                ax = fmaf(wgt, a.x, ax); ay = fmaf(wgt, a.y, ay);
                az = fmaf(wgt, b.x, az); aw = fmaf(wgt, b.y, aw);
            }
        }
    }
    if (act) {
        float di = dinv[n];
        ((float4*)sy[wave])[lane] = make_float4(di * ax, di * ay, di * az, di * aw);
    }
    __syncthreads();   // covers weight staging + sy rows (uniform: all waves valid)

    // ---- epilogue: lane = h ----
    const float* y = sy[wave];
    int h = lane;
    float zp[TP], hp[TP];
    float cz = sczb[h], chb = schb[h];
    #pragma unroll
    for (int t = 0; t < TP; t++) { zp[t] = cz; hp[t] = chb; }
    #pragma unroll
    for (int f = 0; f < FF; f++) {
        float mz = sMz[f * HH + h], mh = sMh[f * HH + h];
        #pragma unroll
        for (int t = 0; t < TP; t++) {
            float yv = y[f * TP + t];           // broadcast read
            zp[t] = fmaf(yv, mz, zp[t]);
            hp[t] = fmaf(yv, mh, hp[t]);
        }
    }
    float acc = 0.0f;
    #pragma unroll
    for (int t = 0; t < TP; t++) {
        float z = 1.0f / (1.0f + __expf(-zp[t]));
        float hv = fmaxf(hp[t], -30.0f);        // guard exp overflow in tanh
        float e = __expf(-2.0f * hv);
        float th = (1.0f - e) / (1.0f + e);
        acc += sprobs[t] * (1.0f - z) * th;
    }
    float r = fmaxf(acc, 0.0f);

    float o[TP];
    #pragma unroll
    for (int jj = 0; jj < TP; jj++) o[jj] = r * sWout[h * TP + jj];
    #pragma unroll
    for (int m = 1; m < 64; m <<= 1) {
        #pragma unroll
        for (int jj = 0; jj < TP; jj++) o[jj] += __shfl_xor(o[jj], m, 64);
    }
    if (lane == 0) {
        float* op = out + (size_t)n * TP;
        #pragma unroll
        for (int jj = 0; jj < TP; jj++) op[jj] = o[jj] + sbout[jj];
    }
}

extern "C" void kernel_launch(void* const* d_in, const int* in_sizes, int n_in,
                              void* d_out, int out_size, void* d_ws, size_t ws_size,
                              hipStream_t stream) {
    const float* x    = (const float*)d_in[0];
    const int*   ei   = (const int*)d_in[1];
    const float* ea   = (const float*)d_in[2];
    const float* Wz   = (const float*)d_in[3];
    const float* bz   = (const float*)d_in[4];
    // d_in[5], d_in[6] = Wr, br  (dead: H0 stays zero in the reference)
    const float* Wh   = (const float*)d_in[7];
    const float* bh   = (const float*)d_in[8];
    const float* Wlz  = (const float*)d_in[9];
    const float* blz  = (const float*)d_in[10];
    // d_in[11], d_in[12] = Wlr, blr (dead)
    const float* Wlh  = (const float*)d_in[13];
    const float* blh  = (const float*)d_in[14];
    const float* att  = (const float*)d_in[15];
    const float* Wout = (const float*)d_in[16];
    const float* bout = (const float*)d_in[17];
    float* out = (float*)d_out;

    char* w = (char*)d_ws;
    auto alloc = [&](size_t bytes) {
        char* p = w;
        w += (bytes + 255) & ~(size_t)255;
        return p;
    };
    int*    counts2 = (int*)alloc((size_t)NCH * NN * 4);
    int2*   csrf    = (int2*)alloc((size_t)NN * CAP * 8);   // 51.2 MB
    float*  dinv    = (float*)alloc(NN * 4);
    __half* xsh     = (__half*)alloc((size_t)NN * FT * 2);
    float*  fold    = (float*)alloc(2048 * 4);
    if ((size_t)(w - (char*)d_ws) > ws_size) return;  // ws too small -> visible failure

    hipLaunchKernelGGL(k_build2,  dim3(NRANGE * NCH), dim3(256), 0, stream, ei, ea, counts2, csrf);
    hipLaunchKernelGGL(k_degxs,   dim3((NN + 3) / 4), dim3(256), 0, stream, x, counts2, csrf, dinv, xsh);
    hipLaunchKernelGGL(k_fold,    dim3(1), dim3(64), 0, stream, Wz, bz, Wh, bh, Wlz, blz, Wlh, blh, att, fold);
    hipLaunchKernelGGL(k_aggmain, dim3(NN / 4), dim3(256), 0, stream,
                       xsh, dinv, counts2, csrf, fold, Wout, bout, out);
}

// Round 16
// 247.068 us; speedup vs baseline: 2.5792x; 2.5792x over previous
//
#include <hip/hip_runtime.h>
#include <hip/hip_fp16.h>

// R15 post-mortem: k_build2 628us (18% occ, 1.5 blocks/CU, latency-bound
// redundant scan) - model ignored TLP starvation. REVERT to R14 pipeline.
// R16 single change vs R14: aggmain gather lane-efficiency. Old: 24/64 lanes
// x 8B per edge (issue-bound, VALU 71%). New: 12 lanes x 16B (uint4) per row,
// 5 edges in flight per wave-round (lanes 0..59, g=lane/12, p=lane%12),
// shfl-tree group reduction at the end. ~2.2x fewer issue slots per edge.

#define NN 50000
#define EE 1600000
#define FT 96        // F*T
#define TP 12
#define FF 8
#define HH 64
#define NPART 196    // ceil(NN/256)

union Cv { ushort4 u; __half2 h[2]; };
union Qv { uint4 u; __half2 h[4]; };

__global__ void __launch_bounds__(256) k_init(int* counts) {
    int n = blockIdx.x * 256 + threadIdx.x;
    if (n < NN) counts[n] = 0;
}

// one int atomic per edge; old value = slot within the row
__global__ void __launch_bounds__(256) k_count(const int* ei, int* counts, int* pos) {
    int e = blockIdx.x * 256 + threadIdx.x;
    if (e < EE) {
        int d = ei[EE + e];
        pos[e] = atomicAdd(&counts[d], 1);
    }
}

// phase 1: per-block sums of counts
__global__ void __launch_bounds__(256) k_psum(const int* counts, int* psum) {
    __shared__ int sh[256];
    int t = threadIdx.x;
    int n = blockIdx.x * 256 + t;
    sh[t] = (n < NN) ? counts[n] : 0;
    __syncthreads();
    for (int off = 128; off > 0; off >>= 1) {
        if (t < off) sh[t] += sh[t + off];
        __syncthreads();
    }
    if (t == 0) psum[blockIdx.x] = sh[0];
}

// phase 2: exclusive scan of the 196 partials (single block)
__global__ void __launch_bounds__(256) k_ptotal(int* psum, int* rowptr) {
    __shared__ int sh[256];
    int t = threadIdx.x;
    int orig = (t < NPART) ? psum[t] : 0;
    sh[t] = orig;
    __syncthreads();
    for (int off = 1; off < 256; off <<= 1) {
        int v = (t >= off) ? sh[t - off] : 0;
        __syncthreads();
        sh[t] += v;
        __syncthreads();
    }
    if (t < NPART) psum[t] = sh[t] - orig;   // exclusive
    if (t == 255) rowptr[NN] = sh[255];      // == EE
}

// phase 3: in-block scan + global offset -> rowptr
__global__ void __launch_bounds__(256) k_write(const int* counts, const int* psum,
                                               int* rowptr) {
    __shared__ int sh[256];
    int t = threadIdx.x;
    int n = blockIdx.x * 256 + t;
    int c = (n < NN) ? counts[n] : 0;
    sh[t] = c;
    __syncthreads();
    for (int off = 1; off < 256; off <<= 1) {
        int v = (t >= off) ? sh[t - off] : 0;
        __syncthreads();
        sh[t] += v;
        __syncthreads();
    }
    if (n < NN) rowptr[n] = psum[blockIdx.x] + sh[t] - c;   // exclusive
}

// atomic-free scatter: slot known from pos[e]
__global__ void __launch_bounds__(256) k_scatter(const int* ei, const float* ea,
                                                 const int* pos, const int* rowptr,
                                                 int2* csr) {
    int e = blockIdx.x * 256 + threadIdx.x;
    if (e < EE) {
        int s = ei[e], d = ei[EE + e];
        csr[rowptr[d] + pos[e]] = make_int2(s, __float_as_int(ea[e]));
    }
}

// wave per node: deg = 1 + sum(ea row); dinv = rsqrt(deg); xs = fp16(dinv * x row)
__global__ void __launch_bounds__(256) k_degxs(const float* __restrict__ x,
                                               const int* __restrict__ rowptr,
                                               const int2* __restrict__ csr,
                                               float* __restrict__ dinv,
                                               __half* __restrict__ xsh) {
    int wave = threadIdx.x >> 6;
    int lane = threadIdx.x & 63;
    int n = blockIdx.x * 4 + wave;
    if (n >= NN) return;
    int jb = rowptr[n], je = rowptr[n + 1];
    float s = 0.0f;
    for (int j = jb + lane; j < je; j += 64) s += __int_as_float(csr[j].y);
    for (int off = 32; off > 0; off >>= 1) s += __shfl_xor(s, off, 64);
    float di = rsqrtf(1.0f + s);   // deg >= 1 always (self loop weight 1, ea >= 0)
    if (lane == 0) dinv[n] = di;
    if (lane < 24) {
        float4 v = ((const float4*)(x + (size_t)n * FT))[lane];
        Cv c;
        c.h[0] = __floats2half2_rn(di * v.x, di * v.y);
        c.h[1] = __floats2half2_rn(di * v.z, di * v.w);
        ((ushort4*)xsh)[(size_t)n * 24 + lane] = c.u;
    }
}

// fold: Mz = Wz @ Wlz_top (8x64), Mh = Wh @ Wlh_top, folded biases, probs = softmax(att)
__global__ void __launch_bounds__(64) k_fold(const float* Wz, const float* bz,
                                             const float* Wh, const float* bh,
                                             const float* Wlz, const float* blz,
                                             const float* Wlh, const float* blh,
                                             const float* att, float* fold) {
    int h = threadIdx.x;   // 0..63
    for (int f = 0; f < FF; f++) {
        float sz = 0.0f, sh = 0.0f;
        for (int k = 0; k < HH; k++) {
            sz += Wz[f * HH + k] * Wlz[k * HH + h];
            sh += Wh[f * HH + k] * Wlh[k * HH + h];
        }
        fold[f * HH + h]       = sz;   // Mz
        fold[512 + f * HH + h] = sh;   // Mh
    }
    float cz = blz[h], ch = blh[h];
    for (int k = 0; k < HH; k++) {
        cz += bz[k] * Wlz[k * HH + h];
        ch += bh[k] * Wlh[k * HH + h];
    }
    fold[1024 + h] = cz;
    fold[1088 + h] = ch;
    if (h < TP) {
        float m = -1e30f;
        for (int t = 0; t < TP; t++) m = fmaxf(m, att[t]);
        float s = 0.0f;
        for (int t = 0; t < TP; t++) s += __expf(att[t] - m);
        fold[1152 + h] = __expf(att[h] - m) / s;
    }
}

// fused gather+epilogue, wave per node.
// Gather: 12 lanes x uint4(16B) per fp16 row; 5 edges in flight per round
// (g = lane/12 picks the edge, p = lane%12 picks the row chunk); group
// partials reduced by shfl at the end. Epilogue: lane = h, shfl butterfly.
// NN = 12500*4 exactly, so every wave owns a valid node (uniform barrier).
__global__ void __launch_bounds__(256) k_aggmain(const __half* __restrict__ xsh,
                                                 const float* __restrict__ dinv,
                                                 const int* __restrict__ rowptr,
                                                 const int2* __restrict__ csr,
                                                 const float* __restrict__ fold,
                                                 const float* __restrict__ Wout,
                                                 const float* __restrict__ bout,
                                                 float* __restrict__ out) {
    __shared__ float sMz[512], sMh[512], sczb[64], schb[64], sprobs[16], sWout[768], sbout[16];
    __shared__ float sy[4][FT];
    for (int i = threadIdx.x; i < 512; i += 256) { sMz[i] = fold[i]; sMh[i] = fold[512 + i]; }
    if (threadIdx.x < 64) {
        sczb[threadIdx.x] = fold[1024 + threadIdx.x];
        schb[threadIdx.x] = fold[1088 + threadIdx.x];
    }
    if (threadIdx.x < TP) {
        sprobs[threadIdx.x] = fold[1152 + threadIdx.x];
        sbout[threadIdx.x]  = bout[threadIdx.x];
    }
    for (int i = threadIdx.x; i < 768; i += 256) sWout[i] = Wout[i];

    int wave = threadIdx.x >> 6;
    int lane = threadIdx.x & 63;
    int n = blockIdx.x * 4 + wave;

    const uint4* xsr = (const uint4*)xsh;   // 12 uint4 per 192B row

    int g = lane / 12;       // edge group 0..4 (5 = always-idle lanes 60..63)
    int p = lane - g * 12;   // row chunk 0..11

    float a0 = 0.f, a1 = 0.f, a2 = 0.f, a3 = 0.f,
          a4 = 0.f, a5 = 0.f, a6 = 0.f, a7 = 0.f;

    // self term: xs[n] with weight 1 (group 0 only)
    if (g == 0) {
        Qv q; q.u = xsr[(size_t)n * 12 + p];
        float2 f0 = __half22float2(q.h[0]);
        float2 f1 = __half22float2(q.h[1]);
        float2 f2 = __half22float2(q.h[2]);
        float2 f3 = __half22float2(q.h[3]);
        a0 = f0.x; a1 = f0.y; a2 = f1.x; a3 = f1.y;
        a4 = f2.x; a5 = f2.y; a6 = f3.x; a7 = f3.y;
    }

    int jb = __builtin_amdgcn_readfirstlane(rowptr[n]);
    int je = __builtin_amdgcn_readfirstlane(rowptr[n + 1]);
    int deg = je - jb;

    for (int base = 0; base < deg; base += 5) {
        int idx = base + g;
        bool valid = (g < 5) && (idx < deg);
        int src = n;
        float wgt = 0.0f;
        if (valid) {
            int2 m = csr[jb + idx];
            src = m.x;
            wgt = __int_as_float(m.y);
        }
        Qv q; q.u = xsr[(size_t)src * 12 + p];
        float2 f0 = __half22float2(q.h[0]);
        float2 f1 = __half22float2(q.h[1]);
        float2 f2 = __half22float2(q.h[2]);
        float2 f3 = __half22float2(q.h[3]);
        a0 = fmaf(wgt, f0.x, a0); a1 = fmaf(wgt, f0.y, a1);
        a2 = fmaf(wgt, f1.x, a2); a3 = fmaf(wgt, f1.y, a3);
        a4 = fmaf(wgt, f2.x, a4); a5 = fmaf(wgt, f2.y, a5);
        a6 = fmaf(wgt, f3.x, a6); a7 = fmaf(wgt, f3.y, a7);
    }

    // reduce the 5 groups into lanes 0..11 (read all sources before adding)
    {
        float t0, t1, t2, t3;
        #define RED(A) \
            t0 = __shfl(A, lane + 12, 64); \
            t1 = __shfl(A, lane + 24, 64); \
            t2 = __shfl(A, lane + 36, 64); \
            t3 = __shfl(A, lane + 48, 64); \
            A = A + t0 + t1 + t2 + t3;
        RED(a0) RED(a1) RED(a2) RED(a3) RED(a4) RED(a5) RED(a6) RED(a7)
        #undef RED
    }

    if (lane < 12) {
        float di = dinv[n];
        ((float4*)sy[wave])[2 * lane]     = make_float4(di * a0, di * a1, di * a2, di * a3);
        ((float4*)sy[wave])[2 * lane + 1] = make_float4(di * a4, di * a5, di * a6, di * a7);
    }
    __syncthreads();   // covers weight staging + sy rows (uniform: all waves valid)

    // ---- epilogue: lane = h ----
    const float* y = sy[wave];
    int h = lane;
    float zp[TP], hp[TP];
    float cz = sczb[h], chb = schb[h];
    #pragma unroll
    for (int t = 0; t < TP; t++) { zp[t] = cz; hp[t] = chb; }
    #pragma unroll
    for (int f = 0; f < FF; f++) {
        float mz = sMz[f * HH + h], mh = sMh[f * HH + h];
        #pragma unroll
        for (int t = 0; t < TP; t++) {
            float yv = y[f * TP + t];           // broadcast read
            zp[t] = fmaf(yv, mz, zp[t]);
            hp[t] = fmaf(yv, mh, hp[t]);
        }
    }
    float acc = 0.0f;
    #pragma unroll
    for (int t = 0; t < TP; t++) {
        float z = 1.0f / (1.0f + __expf(-zp[t]));
        float hv = fmaxf(hp[t], -30.0f);        // guard exp overflow in tanh
        float e = __expf(-2.0f * hv);
        float th = (1.0f - e) / (1.0f + e);
        acc += sprobs[t] * (1.0f - z) * th;
    }
    float r = fmaxf(acc, 0.0f);

    float o[TP];
    #pragma unroll
    for (int jj = 0; jj < TP; jj++) o[jj] = r * sWout[h * TP + jj];
    #pragma unroll
    for (int m = 1; m < 64; m <<= 1) {
        #pragma unroll
        for (int jj = 0; jj < TP; jj++) o[jj] += __shfl_xor(o[jj], m, 64);
    }
    if (lane == 0) {
        float* op = out + (size_t)n * TP;
        #pragma unroll
        for (int jj = 0; jj < TP; jj++) op[jj] = o[jj] + sbout[jj];
    }
}

extern "C" void kernel_launch(void* const* d_in, const int* in_sizes, int n_in,
                              void* d_out, int out_size, void* d_ws, size_t ws_size,
                              hipStream_t stream) {
    const float* x    = (const float*)d_in[0];
    const int*   ei   = (const int*)d_in[1];
    const float* ea   = (const float*)d_in[2];
    const float* Wz   = (const float*)d_in[3];
    const float* bz   = (const float*)d_in[4];
    // d_in[5], d_in[6] = Wr, br  (dead: H0 stays zero in the reference)
    const float* Wh   = (const float*)d_in[7];
    const float* bh   = (const float*)d_in[8];
    const float* Wlz  = (const float*)d_in[9];
    const float* blz  = (const float*)d_in[10];
    // d_in[11], d_in[12] = Wlr, blr (dead)
    const float* Wlh  = (const float*)d_in[13];
    const float* blh  = (const float*)d_in[14];
    const float* att  = (const float*)d_in[15];
    const float* Wout = (const float*)d_in[16];
    const float* bout = (const float*)d_in[17];
    float* out = (float*)d_out;

    char* w = (char*)d_ws;
    auto alloc = [&](size_t bytes) {
        char* p = w;
        w += (bytes + 255) & ~(size_t)255;
        return p;
    };
    int*    counts = (int*)alloc(NN * 4);
    int*    rowptr = (int*)alloc((NN + 1) * 4);
    int*    pos    = (int*)alloc((size_t)EE * 4);
    int2*   csr    = (int2*)alloc((size_t)EE * 8);
    float*  dinv   = (float*)alloc(NN * 4);
    __half* xsh    = (__half*)alloc((size_t)NN * FT * 2);
    float*  fold   = (float*)alloc(2048 * 4);
    int*    psum   = (int*)alloc(NPART * 4);
    if ((size_t)(w - (char*)d_ws) > ws_size) return;  // ws too small -> visible failure

    hipLaunchKernelGGL(k_init,    dim3(NPART), dim3(256), 0, stream, counts);
    hipLaunchKernelGGL(k_count,   dim3((EE + 255) / 256), dim3(256), 0, stream, ei, counts, pos);
    hipLaunchKernelGGL(k_psum,    dim3(NPART), dim3(256), 0, stream, counts, psum);
    hipLaunchKernelGGL(k_ptotal,  dim3(1), dim3(256), 0, stream, psum, rowptr);
    hipLaunchKernelGGL(k_write,   dim3(NPART), dim3(256), 0, stream, counts, psum, rowptr);
    hipLaunchKernelGGL(k_scatter, dim3((EE + 255) / 256), dim3(256), 0, stream, ei, ea, pos, rowptr, csr);
    hipLaunchKernelGGL(k_degxs,   dim3((NN + 3) / 4), dim3(256), 0, stream, x, rowptr, csr, dinv, xsh);
    hipLaunchKernelGGL(k_fold,    dim3(1), dim3(64), 0, stream, Wz, bz, Wh, bh, Wlz, blz, Wlh, blh, att, fold);
    hipLaunchKernelGGL(k_aggmain, dim3(NN / 4), dim3(256), 0, stream,
                       xsh, dinv, rowptr, csr, fold, Wout, bout, out);
}